// Round 6
// baseline (138.354 us; speedup 1.0000x reference)
//
#include <hip/hip_runtime.h>
#include <hip/hip_fp16.h>

// DihedralTerm: E = sum_e force_e * (1 + cos(n_e * phi_e - phase_e))
//
// R6 theory: R2(ITEMS=4)==R4(ITEMS=1)==~52us, and fp16 8B records (R5) only
// -8% => the gather cap is per-L1-LINE-FILL: every divergent lane-request
// misses the 32KB L1 (table is 800KB) and fills a 64B line at 16B/cyc =
// 4cyc/fill; 31250 fills/CU * 4cyc = 52us. Matches all rounds.
// FIX: bypass L1 entirely for gathers. Agent-scope relaxed atomic loads
// must skip the non-coherent L1 on CDNA (sc0) -> data returns L2->VGPR with
// no fill. Predicted: ~20-30us (next wall = L2 request rate per XCD).
//  - coords packed fp16x4 (8B, aligned) in d_ws; table L2-resident (800KB).
//  - plain per-block partial store + tiny reduce kernel (no same-address
//    atomics [R1 lesson], no agent-scope release per block [R3 lesson],
//    no manual sched/waitcnt pinning [R3 lesson]).

#define BLOCK 256

__global__ __launch_bounds__(256) void pad_coords_h4_kernel(
    const float* __restrict__ coords, ushort4* __restrict__ out, int n)
{
    int t = blockIdx.x * blockDim.x + threadIdx.x;
    if (t < n) {
        __half hx = __float2half(coords[3 * t + 0]);
        __half hy = __float2half(coords[3 * t + 1]);
        __half hz = __float2half(coords[3 * t + 2]);
        ushort4 o;
        o.x = __half_as_ushort(hx);
        o.y = __half_as_ushort(hy);
        o.z = __half_as_ushort(hz);
        o.w = 0;
        out[t] = o;
    }
}

__device__ __forceinline__ unsigned long long gather_l2(
    const unsigned long long* __restrict__ p)
{
    // Agent-scope relaxed load: on gfx950 this must bypass the (non-coherent)
    // per-CU L1 -> no 64B line fill, data returns straight from L2.
    return __hip_atomic_load(p, __ATOMIC_RELAXED, __HIP_MEMORY_SCOPE_AGENT);
}

__device__ __forceinline__ void unpack_h4(unsigned long long g,
                                          float& x, float& y, float& z)
{
    union { unsigned long long u; ushort4 s; } cvt;
    cvt.u = g;
    x = __half2float(__ushort_as_half(cvt.s.x));
    y = __half2float(__ushort_as_half(cvt.s.y));
    z = __half2float(__ushort_as_half(cvt.s.z));
}

__global__ __launch_bounds__(BLOCK) void dihedral_kernel(
    const unsigned long long* __restrict__ ch,
    const int* __restrict__ ii, const int* __restrict__ jj,
    const int* __restrict__ kk, const int* __restrict__ ll,
    const float* __restrict__ force, const float* __restrict__ period,
    const float* __restrict__ phase,
    float* __restrict__ partials, int n)
{
    int t = blockIdx.x * BLOCK + threadIdx.x;
    float e = 0.0f;
    if (t < n) {
        int a = ii[t], b = jj[t], c = kk[t], d = ll[t];
        // 4 divergent 8B gathers, L1-bypassed (sc0), L2-resident table
        unsigned long long g0 = gather_l2(ch + a);
        unsigned long long g1 = gather_l2(ch + b);
        unsigned long long g2 = gather_l2(ch + c);
        unsigned long long g3 = gather_l2(ch + d);
        float F = force[t], PN = period[t], PH = phase[t];

        float p0x, p0y, p0z, p1x, p1y, p1z, p2x, p2y, p2z, p3x, p3y, p3z;
        unpack_h4(g0, p0x, p0y, p0z);
        unpack_h4(g1, p1x, p1y, p1z);
        unpack_h4(g2, p2x, p2y, p2z);
        unpack_h4(g3, p3x, p3y, p3z);

        float v1x = p0x - p1x, v1y = p0y - p1y, v1z = p0z - p1z;
        float v2x = p2x - p1x, v2y = p2y - p1y, v2z = p2z - p1z;
        float v3x = p2x - p3x, v3y = p2y - p3y, v3z = p2z - p3z;

        float ax = v1y * v2z - v1z * v2y;
        float ay = v1z * v2x - v1x * v2z;
        float az = v1x * v2y - v1y * v2x;
        float bx = v2y * v3z - v2z * v3y;
        float by = v2z * v3x - v2x * v3z;
        float bz = v2x * v3y - v2y * v3x;

        float d12 = ax * bx + ay * by + az * bz;
        float na2 = ax * ax + ay * ay + az * az;
        float nb2 = bx * bx + by * by + bz * bz;
        float m = fmaxf(na2 * nb2, 1e-24f);
        float cphi = d12 * __builtin_amdgcn_rsqf(m);
        cphi = fminf(fmaxf(cphi, -1.0f), 1.0f);
        float s2 = fmaxf(1.0f - cphi * cphi, 0.0f);
        float sphi = __builtin_amdgcn_sqrtf(s2);
        float sdot = v1x * bx + v1y * by + v1z * bz;
        sphi = (sdot < 0.0f) ? -sphi : sphi;

        // n = |period|, integer in {1..4}; Chebyshev multiple-angle
        int np = (int)(fabsf(PN) + 0.5f);
        float cn = cphi, sn = sphi;
#pragma unroll
        for (int r = 1; r < 4; ++r) {
            float cnew = cn * cphi - sn * sphi;
            float snew = sn * cphi + cn * sphi;
            bool take = (r < np);
            cn = take ? cnew : cn;
            sn = take ? snew : sn;
        }

        float cp = __cosf(PH);
        float sp = __sinf(PH);
        e = F * (1.0f + cn * cp + sn * sp);
    }

    // block reduction: wave shfl -> LDS -> one plain store per block
#pragma unroll
    for (int off = 32; off > 0; off >>= 1)
        e += __shfl_down(e, off, 64);

    __shared__ float wsum[BLOCK / 64];
    int lane = threadIdx.x & 63;
    int wv = threadIdx.x >> 6;
    if (lane == 0) wsum[wv] = e;
    __syncthreads();
    if (threadIdx.x == 0) {
        float tot = 0.0f;
#pragma unroll
        for (int w = 0; w < BLOCK / 64; ++w) tot += wsum[w];
        partials[blockIdx.x] = tot;
    }
}

__global__ __launch_bounds__(1024) void reduce_kernel(
    const float* __restrict__ partials, int m, float* __restrict__ out)
{
    float e = 0.0f;
    for (int i = threadIdx.x; i < m; i += 1024) e += partials[i];
#pragma unroll
    for (int off = 32; off > 0; off >>= 1)
        e += __shfl_down(e, off, 64);
    __shared__ float wsum[16];
    int lane = threadIdx.x & 63;
    int wv = threadIdx.x >> 6;
    if (lane == 0) wsum[wv] = e;
    __syncthreads();
    if (threadIdx.x == 0) {
        float tot = 0.0f;
#pragma unroll
        for (int w = 0; w < 16; ++w) tot += wsum[w];
        out[0] = tot;
    }
}

extern "C" void kernel_launch(void* const* d_in, const int* in_sizes, int n_in,
                              void* d_out, int out_size, void* d_ws, size_t ws_size,
                              hipStream_t stream) {
    const float* coords = (const float*)d_in[0];
    const int* ii = (const int*)d_in[1];
    const int* jj = (const int*)d_in[2];
    const int* kk = (const int*)d_in[3];
    const int* ll = (const int*)d_in[4];
    const float* force = (const float*)d_in[5];
    const float* period = (const float*)d_in[6];
    const float* phase = (const float*)d_in[7];

    int natoms = in_sizes[0] / 3;
    int n = in_sizes[1];
    float* out = (float*)d_out;

    int blocks = (n + BLOCK - 1) / BLOCK;

    size_t pad_bytes = (size_t)natoms * sizeof(ushort4);
    size_t part_off = (pad_bytes + 255) & ~(size_t)255;
    char* w = (char*)d_ws;

    ushort4* ch = (ushort4*)w;
    float* partials = (float*)(w + part_off);

    pad_coords_h4_kernel<<<(natoms + 255) / 256, 256, 0, stream>>>(coords, ch, natoms);
    dihedral_kernel<<<blocks, BLOCK, 0, stream>>>(
        (const unsigned long long*)ch, ii, jj, kk, ll, force, period, phase,
        partials, n);
    reduce_kernel<<<1, 1024, 0, stream>>>(partials, blocks, out);
}

// Round 7
// 134.838 us; speedup vs baseline: 1.0261x; 1.0261x over previous
//
#include <hip/hip_runtime.h>
#include <hip/hip_fp16.h>

// DihedralTerm: E = sum_e force_e * (1 + cos(n_e * phi_e - phase_e))
//
// R7 = revert to R5 (best measured: 47.0-49.7 us kernel), after R6's
// L1-bypass experiment regressed (51-57 us).
//
// ROOFLINE MODEL (supported by R1-R6 invariance):
//   The 8M divergent 8B gathers are bound by the per-CU miss-queue:
//   ~64 outstanding lane-requests x ~250cy L2 latency => ~0.25 req/cyc/CU
//   => 8M / 256CU / 0.25 / 2.4GHz ~= 52 us. Invariant to ILP (R2=R4),
//   occupancy (R4), record size 16B->8B (R5), L1 bypass (R6). Request
//   count is algorithmically irreducible (i.i.d. uniform indices: no
//   dedup/coalescing; sorting costs more HBM traffic than it saves;
//   table >> LDS/L1).
//
// Structure:
//  - coords packed fp16x4 (8B aligned) in d_ws; table (800KB) L2-resident.
//  - ITEMS=1, VGPR=16 -> 8 waves/SIMD hide the idx->gather chain.
//  - per-block partial via plain store + tiny reduce kernel (no
//    same-address atomics [R1], no agent-scope release fences [R3],
//    no sched_barrier pinning [R3]).

#define BLOCK 256

__global__ __launch_bounds__(256) void pad_coords_h4_kernel(
    const float* __restrict__ coords, ushort4* __restrict__ out, int n)
{
    int t = blockIdx.x * blockDim.x + threadIdx.x;
    if (t < n) {
        __half hx = __float2half(coords[3 * t + 0]);
        __half hy = __float2half(coords[3 * t + 1]);
        __half hz = __float2half(coords[3 * t + 2]);
        ushort4 o;
        o.x = __half_as_ushort(hx);
        o.y = __half_as_ushort(hy);
        o.z = __half_as_ushort(hz);
        o.w = 0;
        out[t] = o;
    }
}

__device__ __forceinline__ void unpack_h4(const ushort4 g, float& x, float& y, float& z)
{
    x = __half2float(__ushort_as_half(g.x));
    y = __half2float(__ushort_as_half(g.y));
    z = __half2float(__ushort_as_half(g.z));
}

__global__ __launch_bounds__(BLOCK) void dihedral_kernel(
    const ushort4* __restrict__ ch,
    const int* __restrict__ ii, const int* __restrict__ jj,
    const int* __restrict__ kk, const int* __restrict__ ll,
    const float* __restrict__ force, const float* __restrict__ period,
    const float* __restrict__ phase,
    float* __restrict__ partials, int n)
{
    int t = blockIdx.x * BLOCK + threadIdx.x;
    float e = 0.0f;
    if (t < n) {
        int a = ii[t], b = jj[t], c = kk[t], d = ll[t];
        // 4 divergent 8B gathers (L2-resident 800KB table)
        ushort4 g0 = ch[a], g1 = ch[b], g2 = ch[c], g3 = ch[d];
        float F = force[t], PN = period[t], PH = phase[t];

        float p0x, p0y, p0z, p1x, p1y, p1z, p2x, p2y, p2z, p3x, p3y, p3z;
        unpack_h4(g0, p0x, p0y, p0z);
        unpack_h4(g1, p1x, p1y, p1z);
        unpack_h4(g2, p2x, p2y, p2z);
        unpack_h4(g3, p3x, p3y, p3z);

        float v1x = p0x - p1x, v1y = p0y - p1y, v1z = p0z - p1z;
        float v2x = p2x - p1x, v2y = p2y - p1y, v2z = p2z - p1z;
        float v3x = p2x - p3x, v3y = p2y - p3y, v3z = p2z - p3z;

        float ax = v1y * v2z - v1z * v2y;
        float ay = v1z * v2x - v1x * v2z;
        float az = v1x * v2y - v1y * v2x;
        float bx = v2y * v3z - v2z * v3y;
        float by = v2z * v3x - v2x * v3z;
        float bz = v2x * v3y - v2y * v3x;

        float d12 = ax * bx + ay * by + az * bz;
        float na2 = ax * ax + ay * ay + az * az;
        float nb2 = bx * bx + by * by + bz * bz;
        float m = fmaxf(na2 * nb2, 1e-24f);
        float cphi = d12 * __builtin_amdgcn_rsqf(m);
        cphi = fminf(fmaxf(cphi, -1.0f), 1.0f);
        float s2 = fmaxf(1.0f - cphi * cphi, 0.0f);
        float sphi = __builtin_amdgcn_sqrtf(s2);
        float sdot = v1x * bx + v1y * by + v1z * bz;
        sphi = (sdot < 0.0f) ? -sphi : sphi;

        // n = |period|, integer in {1..4}; Chebyshev multiple-angle
        int np = (int)(fabsf(PN) + 0.5f);
        float cn = cphi, sn = sphi;
#pragma unroll
        for (int r = 1; r < 4; ++r) {
            float cnew = cn * cphi - sn * sphi;
            float snew = sn * cphi + cn * sphi;
            bool take = (r < np);
            cn = take ? cnew : cn;
            sn = take ? snew : sn;
        }

        float cp = __cosf(PH);
        float sp = __sinf(PH);
        e = F * (1.0f + cn * cp + sn * sp);
    }

    // block reduction: wave shfl -> LDS -> one plain store per block
#pragma unroll
    for (int off = 32; off > 0; off >>= 1)
        e += __shfl_down(e, off, 64);

    __shared__ float wsum[BLOCK / 64];
    int lane = threadIdx.x & 63;
    int wv = threadIdx.x >> 6;
    if (lane == 0) wsum[wv] = e;
    __syncthreads();
    if (threadIdx.x == 0) {
        float tot = 0.0f;
#pragma unroll
        for (int w = 0; w < BLOCK / 64; ++w) tot += wsum[w];
        partials[blockIdx.x] = tot;
    }
}

__global__ __launch_bounds__(1024) void reduce_kernel(
    const float* __restrict__ partials, int m, float* __restrict__ out)
{
    float e = 0.0f;
    for (int i = threadIdx.x; i < m; i += 1024) e += partials[i];
#pragma unroll
    for (int off = 32; off > 0; off >>= 1)
        e += __shfl_down(e, off, 64);
    __shared__ float wsum[16];
    int lane = threadIdx.x & 63;
    int wv = threadIdx.x >> 6;
    if (lane == 0) wsum[wv] = e;
    __syncthreads();
    if (threadIdx.x == 0) {
        float tot = 0.0f;
#pragma unroll
        for (int w = 0; w < 16; ++w) tot += wsum[w];
        out[0] = tot;
    }
}

extern "C" void kernel_launch(void* const* d_in, const int* in_sizes, int n_in,
                              void* d_out, int out_size, void* d_ws, size_t ws_size,
                              hipStream_t stream) {
    const float* coords = (const float*)d_in[0];
    const int* ii = (const int*)d_in[1];
    const int* jj = (const int*)d_in[2];
    const int* kk = (const int*)d_in[3];
    const int* ll = (const int*)d_in[4];
    const float* force = (const float*)d_in[5];
    const float* period = (const float*)d_in[6];
    const float* phase = (const float*)d_in[7];

    int natoms = in_sizes[0] / 3;
    int n = in_sizes[1];
    float* out = (float*)d_out;

    int blocks = (n + BLOCK - 1) / BLOCK;

    size_t pad_bytes = (size_t)natoms * sizeof(ushort4);
    size_t part_off = (pad_bytes + 255) & ~(size_t)255;
    char* w = (char*)d_ws;

    ushort4* ch = (ushort4*)w;
    float* partials = (float*)(w + part_off);

    pad_coords_h4_kernel<<<(natoms + 255) / 256, 256, 0, stream>>>(coords, ch, natoms);
    dihedral_kernel<<<blocks, BLOCK, 0, stream>>>(
        ch, ii, jj, kk, ll, force, period, phase, partials, n);
    reduce_kernel<<<1, 1024, 0, stream>>>(partials, blocks, out);
}